// Round 1
// baseline (1176.584 us; speedup 1.0000x reference)
//
#include <hip/hip_runtime.h>

#define HID 128
#define EMB 256
#define NL 3
#define NEDGE 640000
#define NNODE 40000

typedef unsigned short u16;
typedef __attribute__((ext_vector_type(8))) __bf16 bf16x8;
typedef __attribute__((ext_vector_type(4))) float f32x4;

union Frag {
  uint4 q;
  bf16x8 v;
  u16 u[8];
};

__device__ inline u16 f2b(float f) {
  unsigned u = __float_as_uint(f);
  unsigned r = (u + 0x7fffu + ((u >> 16) & 1u)) >> 16;  // RNE
  return (u16)r;
}
__device__ inline float b2f(u16 h) { return __uint_as_float(((unsigned)h) << 16); }

// swizzled index into a [64][EMB] bf16 LDS tile (row stride 512 B).
// XOR byte-bits 4..6 with row&7: 8-row stripes cover all 32 banks (G4).
__device__ inline int sidx(int row, int k) {
  return row * EMB + ((((k) << 1) ^ ((row & 7) << 4)) >> 1);
}

// ---------------- weight prep: f32 -> bf16, transposed to [col][k] ----------
__global__ void prep_weights(const float* __restrict__ Wup, const float* __restrict__ Wlins,
                             u16* __restrict__ wtup, u16* __restrict__ wtlin) {
  int t = blockIdx.x * blockDim.x + threadIdx.x;
  if (t < EMB * HID) {
    int c = t >> 7, k = t & (HID - 1);
    wtup[t] = f2b(Wup[k * EMB + c]);
  }
  if (t < NL * EMB * EMB) {
    int l = t >> 16, r = t & 0xFFFF;
    int c = r >> 8, k = r & 255;
    wtlin[t] = f2b(Wlins[l * EMB * EMB + k * EMB + c]);
  }
}

// ---------------- scatter-sum: v[node] += e2[edge] ----------------
__global__ void scatter_kernel(const float* __restrict__ e2, const int* __restrict__ idx,
                               float* __restrict__ v) {
  int g = blockIdx.x * (blockDim.x >> 5) + (threadIdx.x >> 5);  // edge id, 32 lanes/edge
  int lane = threadIdx.x & 31;
  if (g >= NEDGE) return;
  int node = idx[g];
  const float4 val = *reinterpret_cast<const float4*>(e2 + (size_t)g * HID + lane * 4);
  float* dst = v + (size_t)node * HID + lane * 4;
  atomicAdd(dst + 0, val.x);
  atomicAdd(dst + 1, val.y);
  atomicAdd(dst + 2, val.z);
  atomicAdd(dst + 3, val.w);
}

// ---------------- fused MLP: 64 rows per block, 4 waves, bf16 MFMA ----------
__global__ __launch_bounds__(256, 2) void mlp_kernel(
    const float* __restrict__ v,      // [N][HID] f32 (scatter output)
    const u16* __restrict__ wtup,     // [EMB][HID] bf16 = W_up^T
    const float* __restrict__ bup,    // [EMB]
    const u16* __restrict__ wtlin,    // [NL][EMB][EMB] bf16 = W_lin^T per layer
    const float* __restrict__ blin,   // [NL][EMB]
    const float* __restrict__ wout,   // [EMB] f32
    float* __restrict__ out) {        // [N]
  __shared__ __attribute__((aligned(16))) u16 actA[64 * EMB];
  __shared__ __attribute__((aligned(16))) u16 actB[64 * EMB];

  const int tid = threadIdx.x;
  const int wv = tid >> 6;     // wave 0..3 owns cols wv*64 .. wv*64+63
  const int lane = tid & 63;
  const int l16 = lane & 15;
  const int kg = lane >> 4;    // k-group 0..3
  const int row0 = blockIdx.x * 64;

  f32x4 acc[4][4];

  // ---------- layer 1: v[64x128] @ W_up + b_up (no activation) ----------
#pragma unroll
  for (int rt = 0; rt < 4; ++rt)
#pragma unroll
    for (int ct = 0; ct < 4; ++ct)
      acc[rt][ct] = (f32x4)(0.f);

#pragma unroll
  for (int ks = 0; ks < HID / 32; ++ks) {
    Frag bf[4];
#pragma unroll
    for (int ct = 0; ct < 4; ++ct) {
      int col = wv * 64 + ct * 16 + l16;
      bf[ct].q = *reinterpret_cast<const uint4*>(wtup + col * HID + ks * 32 + kg * 8);
    }
#pragma unroll
    for (int rt = 0; rt < 4; ++rt) {
      const float* src = v + (size_t)(row0 + rt * 16 + l16) * HID + ks * 32 + kg * 8;
      float4 x0 = *reinterpret_cast<const float4*>(src);
      float4 x1 = *reinterpret_cast<const float4*>(src + 4);
      Frag af;
      af.u[0] = f2b(x0.x); af.u[1] = f2b(x0.y); af.u[2] = f2b(x0.z); af.u[3] = f2b(x0.w);
      af.u[4] = f2b(x1.x); af.u[5] = f2b(x1.y); af.u[6] = f2b(x1.z); af.u[7] = f2b(x1.w);
#pragma unroll
      for (int ct = 0; ct < 4; ++ct)
        acc[rt][ct] = __builtin_amdgcn_mfma_f32_16x16x32_bf16(af.v, bf[ct].v, acc[rt][ct], 0, 0, 0);
    }
  }
  // epilogue: + bias, store bf16 into actA (C layout: row=(lane>>4)*4+i, col=lane&15)
#pragma unroll
  for (int ct = 0; ct < 4; ++ct) {
    int col = wv * 64 + ct * 16 + l16;
    float b = bup[col];
#pragma unroll
    for (int rt = 0; rt < 4; ++rt)
#pragma unroll
      for (int i = 0; i < 4; ++i)
        actA[sidx(rt * 16 + kg * 4 + i, col)] = f2b(acc[rt][ct][i] + b);
  }
  __syncthreads();

  // ---------- layers 2..4: silu(h @ W + b) ----------
  const u16* sbuf = actA;
  u16* dbuf = actB;
  for (int l = 0; l < NL; ++l) {
    const u16* wt = wtlin + l * EMB * EMB;
    const float* bl = blin + l * EMB;
#pragma unroll
    for (int rt = 0; rt < 4; ++rt)
#pragma unroll
      for (int ct = 0; ct < 4; ++ct)
        acc[rt][ct] = (f32x4)(0.f);

#pragma unroll
    for (int ks = 0; ks < EMB / 32; ++ks) {
      Frag bf[4];
#pragma unroll
      for (int ct = 0; ct < 4; ++ct) {
        int col = wv * 64 + ct * 16 + l16;
        bf[ct].q = *reinterpret_cast<const uint4*>(wt + col * EMB + ks * 32 + kg * 8);
      }
#pragma unroll
      for (int rt = 0; rt < 4; ++rt) {
        Frag af;
        af.q = *reinterpret_cast<const uint4*>(&sbuf[sidx(rt * 16 + l16, ks * 32 + kg * 8)]);
#pragma unroll
        for (int ct = 0; ct < 4; ++ct)
          acc[rt][ct] = __builtin_amdgcn_mfma_f32_16x16x32_bf16(af.v, bf[ct].v, acc[rt][ct], 0, 0, 0);
      }
    }
    // epilogue: bias + silu + store
#pragma unroll
    for (int ct = 0; ct < 4; ++ct) {
      int col = wv * 64 + ct * 16 + l16;
      float b = bl[col];
#pragma unroll
      for (int rt = 0; rt < 4; ++rt)
#pragma unroll
        for (int i = 0; i < 4; ++i) {
          float x = acc[rt][ct][i] + b;
          float s = x / (1.f + __expf(-x));
          dbuf[sidx(rt * 16 + kg * 4 + i, col)] = f2b(s);
        }
    }
    __syncthreads();
    const u16* tmp = dbuf;
    dbuf = const_cast<u16*>(sbuf);
    sbuf = tmp;
  }

  // ---------- final projection: out = h @ W_out (K=256, N=1) ----------
  // sbuf now holds layer-3 output. 4 threads per row, 64 elems each.
  int r = tid >> 2;
  int part = tid & 3;
  float s = 0.f;
  int k0 = part * 64;
  for (int k = k0; k < k0 + 64; ++k)
    s += b2f(sbuf[sidx(r, k)]) * wout[k];
  s += __shfl_xor(s, 1);
  s += __shfl_xor(s, 2);
  if (part == 0) out[row0 + r] = s;
}

extern "C" void kernel_launch(void* const* d_in, const int* in_sizes, int n_in,
                              void* d_out, int out_size, void* d_ws, size_t ws_size,
                              hipStream_t stream) {
  // inputs: 0=e1(unused) 1=e2 2=i 3=num_nodes 4=W_up 5=b_up 6=W_lins 7=b_lins 8=W_out
  const float* e2 = (const float*)d_in[1];
  const int* idx = (const int*)d_in[2];
  const float* Wup = (const float*)d_in[4];
  const float* bup = (const float*)d_in[5];
  const float* Wlins = (const float*)d_in[6];
  const float* blin = (const float*)d_in[7];
  const float* Wout = (const float*)d_in[8];
  float* out = (float*)d_out;

  // workspace layout
  float* v = (float*)d_ws;                                   // N*HID f32 = 20.48 MB
  size_t off = (size_t)NNODE * HID * sizeof(float);
  u16* wtup = (u16*)((char*)d_ws + off);                     // EMB*HID bf16
  off += (size_t)EMB * HID * sizeof(u16);
  u16* wtlin = (u16*)((char*)d_ws + off);                    // NL*EMB*EMB bf16

  hipMemsetAsync(v, 0, (size_t)NNODE * HID * sizeof(float), stream);
  prep_weights<<<(NL * EMB * EMB + 255) / 256, 256, 0, stream>>>(Wup, Wlins, wtup, wtlin);
  scatter_kernel<<<NEDGE / 8, 256, 0, stream>>>(e2, idx, v);
  mlp_kernel<<<NNODE / 64, 256, 0, stream>>>(v, wtup, bup, wtlin, blin, Wout, out);
}

// Round 2
// 303.643 us; speedup vs baseline: 3.8749x; 3.8749x over previous
//
#include <hip/hip_runtime.h>

#define HID 128
#define EMB 256
#define NL 3
#define NEDGE 640000
#define NNODE 40000
#define SCAN_T 1024
#define CHUNK 40  // ceil(NNODE / SCAN_T)

typedef unsigned short u16;
typedef __attribute__((ext_vector_type(8))) __bf16 bf16x8;
typedef __attribute__((ext_vector_type(4))) float f32x4;

union Frag {
  uint4 q;
  bf16x8 v;
  u16 u[8];
};

__device__ inline u16 f2b(float f) {
  unsigned u = __float_as_uint(f);
  unsigned r = (u + 0x7fffu + ((u >> 16) & 1u)) >> 16;  // RNE
  return (u16)r;
}
__device__ inline float b2f(u16 h) { return __uint_as_float(((unsigned)h) << 16); }

// swizzled index into a [64][EMB] bf16 LDS tile (row stride 512 B).
// XOR byte-bits 4..6 with row&7: 8-row stripes cover all 32 banks (G4).
__device__ inline int sidx(int row, int k) {
  return row * EMB + ((((k) << 1) ^ ((row & 7) << 4)) >> 1);
}

// ---------------- weight prep: f32 -> bf16, transposed to [col][k] ----------
__global__ void prep_weights(const float* __restrict__ Wup, const float* __restrict__ Wlins,
                             u16* __restrict__ wtup, u16* __restrict__ wtlin) {
  int t = blockIdx.x * blockDim.x + threadIdx.x;
  if (t < EMB * HID) {
    int c = t >> 7, k = t & (HID - 1);
    wtup[t] = f2b(Wup[k * EMB + c]);
  }
  if (t < NL * EMB * EMB) {
    int l = t >> 16, r = t & 0xFFFF;
    int c = r >> 8, k = r & 255;
    wtlin[t] = f2b(Wlins[l * EMB * EMB + k * EMB + c]);
  }
}

// ---------------- CSR build ----------------
__global__ void count_kernel(const int* __restrict__ idx, int* __restrict__ cnt) {
  int e = blockIdx.x * blockDim.x + threadIdx.x;
  if (e < NEDGE) atomicAdd(&cnt[idx[e]], 1);
}

__global__ __launch_bounds__(SCAN_T) void scan_kernel(const int* __restrict__ cnt,
                                                      int* __restrict__ off,
                                                      int* __restrict__ cur) {
  __shared__ int s[SCAN_T];
  int t = threadIdx.x;
  int base = t * CHUNK;
  int c[CHUNK];
  int local = 0;
#pragma unroll
  for (int j = 0; j < CHUNK; ++j) {
    int i = base + j;
    c[j] = (i < NNODE) ? cnt[i] : 0;
    local += c[j];
  }
  s[t] = local;
  __syncthreads();
  for (int d = 1; d < SCAN_T; d <<= 1) {
    int tmp = (t >= d) ? s[t - d] : 0;
    __syncthreads();
    s[t] += tmp;
    __syncthreads();
  }
  int run = (t == 0) ? 0 : s[t - 1];  // exclusive prefix of per-thread sums
#pragma unroll
  for (int j = 0; j < CHUNK; ++j) {
    int i = base + j;
    if (i < NNODE) { off[i] = run; cur[i] = run; }
    run += c[j];
  }
}

__global__ void fill_kernel(const int* __restrict__ idx, int* __restrict__ cur,
                            int* __restrict__ bucket) {
  int e = blockIdx.x * blockDim.x + threadIdx.x;
  if (e < NEDGE) {
    int p = atomicAdd(&cur[idx[e]], 1);
    bucket[p] = e;
  }
}

// ---------------- gather-sum: v[node] = sum of its e2 rows ----------------
__global__ __launch_bounds__(256) void gather_kernel(const float* __restrict__ e2,
                                                     const int* __restrict__ bucket,
                                                     const int* __restrict__ off,
                                                     const int* __restrict__ cnt,
                                                     float* __restrict__ v) {
  int node = blockIdx.x * 8 + (threadIdx.x >> 5);  // 32 lanes per node
  if (node >= NNODE) return;
  int lane = threadIdx.x & 31;
  int s = off[node];
  int n = cnt[node];
  float4 acc = {0.f, 0.f, 0.f, 0.f};
  int e = (n > 0) ? bucket[s] : 0;
  for (int j = 0; j < n; ++j) {
    int enext = (j + 1 < n) ? bucket[s + j + 1] : 0;  // prefetch next edge id
    const float4 x = *reinterpret_cast<const float4*>(e2 + (size_t)e * HID + lane * 4);
    acc.x += x.x; acc.y += x.y; acc.z += x.z; acc.w += x.w;
    e = enext;
  }
  *reinterpret_cast<float4*>(v + (size_t)node * HID + lane * 4) = acc;
}

// ---------------- fused MLP: 64 rows per block, 4 waves, bf16 MFMA ----------
__global__ __launch_bounds__(256, 2) void mlp_kernel(
    const float* __restrict__ v,      // [N][HID] f32 (gather output)
    const u16* __restrict__ wtup,     // [EMB][HID] bf16 = W_up^T
    const float* __restrict__ bup,    // [EMB]
    const u16* __restrict__ wtlin,    // [NL][EMB][EMB] bf16 = W_lin^T per layer
    const float* __restrict__ blin,   // [NL][EMB]
    const float* __restrict__ wout,   // [EMB] f32
    float* __restrict__ out) {        // [N]
  __shared__ __attribute__((aligned(16))) u16 actA[64 * EMB];
  __shared__ __attribute__((aligned(16))) u16 actB[64 * EMB];

  const int tid = threadIdx.x;
  const int wv = tid >> 6;     // wave 0..3 owns cols wv*64 .. wv*64+63
  const int lane = tid & 63;
  const int l16 = lane & 15;
  const int kg = lane >> 4;    // k-group 0..3
  const int row0 = blockIdx.x * 64;

  f32x4 acc[4][4];

  // ---------- layer 1: v[64x128] @ W_up + b_up (no activation) ----------
#pragma unroll
  for (int rt = 0; rt < 4; ++rt)
#pragma unroll
    for (int ct = 0; ct < 4; ++ct)
      acc[rt][ct] = (f32x4)(0.f);

#pragma unroll
  for (int ks = 0; ks < HID / 32; ++ks) {
    Frag bf[4];
#pragma unroll
    for (int ct = 0; ct < 4; ++ct) {
      int col = wv * 64 + ct * 16 + l16;
      bf[ct].q = *reinterpret_cast<const uint4*>(wtup + col * HID + ks * 32 + kg * 8);
    }
#pragma unroll
    for (int rt = 0; rt < 4; ++rt) {
      const float* src = v + (size_t)(row0 + rt * 16 + l16) * HID + ks * 32 + kg * 8;
      float4 x0 = *reinterpret_cast<const float4*>(src);
      float4 x1 = *reinterpret_cast<const float4*>(src + 4);
      Frag af;
      af.u[0] = f2b(x0.x); af.u[1] = f2b(x0.y); af.u[2] = f2b(x0.z); af.u[3] = f2b(x0.w);
      af.u[4] = f2b(x1.x); af.u[5] = f2b(x1.y); af.u[6] = f2b(x1.z); af.u[7] = f2b(x1.w);
#pragma unroll
      for (int ct = 0; ct < 4; ++ct)
        acc[rt][ct] = __builtin_amdgcn_mfma_f32_16x16x32_bf16(af.v, bf[ct].v, acc[rt][ct], 0, 0, 0);
    }
  }
  // epilogue: + bias, store bf16 into actA (C layout: row=(lane>>4)*4+i, col=lane&15)
#pragma unroll
  for (int ct = 0; ct < 4; ++ct) {
    int col = wv * 64 + ct * 16 + l16;
    float b = bup[col];
#pragma unroll
    for (int rt = 0; rt < 4; ++rt)
#pragma unroll
      for (int i = 0; i < 4; ++i)
        actA[sidx(rt * 16 + kg * 4 + i, col)] = f2b(acc[rt][ct][i] + b);
  }
  __syncthreads();

  // ---------- layers 2..4: silu(h @ W + b) ----------
  const u16* sbuf = actA;
  u16* dbuf = actB;
  for (int l = 0; l < NL; ++l) {
    const u16* wt = wtlin + l * EMB * EMB;
    const float* bl = blin + l * EMB;
#pragma unroll
    for (int rt = 0; rt < 4; ++rt)
#pragma unroll
      for (int ct = 0; ct < 4; ++ct)
        acc[rt][ct] = (f32x4)(0.f);

#pragma unroll
    for (int ks = 0; ks < EMB / 32; ++ks) {
      Frag bf[4];
#pragma unroll
      for (int ct = 0; ct < 4; ++ct) {
        int col = wv * 64 + ct * 16 + l16;
        bf[ct].q = *reinterpret_cast<const uint4*>(wt + col * EMB + ks * 32 + kg * 8);
      }
#pragma unroll
      for (int rt = 0; rt < 4; ++rt) {
        Frag af;
        af.q = *reinterpret_cast<const uint4*>(&sbuf[sidx(rt * 16 + l16, ks * 32 + kg * 8)]);
#pragma unroll
        for (int ct = 0; ct < 4; ++ct)
          acc[rt][ct] = __builtin_amdgcn_mfma_f32_16x16x32_bf16(af.v, bf[ct].v, acc[rt][ct], 0, 0, 0);
      }
    }
    // epilogue: bias + silu + store
#pragma unroll
    for (int ct = 0; ct < 4; ++ct) {
      int col = wv * 64 + ct * 16 + l16;
      float b = bl[col];
#pragma unroll
      for (int rt = 0; rt < 4; ++rt)
#pragma unroll
        for (int i = 0; i < 4; ++i) {
          float x = acc[rt][ct][i] + b;
          float s = x / (1.f + __expf(-x));
          dbuf[sidx(rt * 16 + kg * 4 + i, col)] = f2b(s);
        }
    }
    __syncthreads();
    const u16* tmp = dbuf;
    dbuf = const_cast<u16*>(sbuf);
    sbuf = tmp;
  }

  // ---------- final projection: out = h @ W_out (K=256, N=1) ----------
  int r = tid >> 2;
  int part = tid & 3;
  float s = 0.f;
  int k0 = part * 64;
  for (int k = k0; k < k0 + 64; ++k)
    s += b2f(sbuf[sidx(r, k)]) * wout[k];
  s += __shfl_xor(s, 1);
  s += __shfl_xor(s, 2);
  if (part == 0) out[row0 + r] = s;
}

extern "C" void kernel_launch(void* const* d_in, const int* in_sizes, int n_in,
                              void* d_out, int out_size, void* d_ws, size_t ws_size,
                              hipStream_t stream) {
  // inputs: 0=e1(unused) 1=e2 2=i 3=num_nodes 4=W_up 5=b_up 6=W_lins 7=b_lins 8=W_out
  const float* e2 = (const float*)d_in[1];
  const int* idx = (const int*)d_in[2];
  const float* Wup = (const float*)d_in[4];
  const float* bup = (const float*)d_in[5];
  const float* Wlins = (const float*)d_in[6];
  const float* blin = (const float*)d_in[7];
  const float* Wout = (const float*)d_in[8];
  float* out = (float*)d_out;

  // workspace layout
  char* ws = (char*)d_ws;
  size_t off_b = 0;
  float* v = (float*)(ws + off_b);            off_b += (size_t)NNODE * HID * sizeof(float);   // 20.48 MB
  u16* wtup = (u16*)(ws + off_b);             off_b += (size_t)EMB * HID * sizeof(u16);
  u16* wtlin = (u16*)(ws + off_b);            off_b += (size_t)NL * EMB * EMB * sizeof(u16);
  int* cnt = (int*)(ws + off_b);              off_b += (size_t)NNODE * sizeof(int);
  int* noff = (int*)(ws + off_b);             off_b += (size_t)NNODE * sizeof(int);
  int* cur = (int*)(ws + off_b);              off_b += (size_t)NNODE * sizeof(int);
  int* bucket = (int*)(ws + off_b);           off_b += (size_t)NEDGE * sizeof(int);

  hipMemsetAsync(cnt, 0, (size_t)NNODE * sizeof(int), stream);
  prep_weights<<<(NL * EMB * EMB + 255) / 256, 256, 0, stream>>>(Wup, Wlins, wtup, wtlin);
  count_kernel<<<(NEDGE + 255) / 256, 256, 0, stream>>>(idx, cnt);
  scan_kernel<<<1, SCAN_T, 0, stream>>>(cnt, noff, cur);
  fill_kernel<<<(NEDGE + 255) / 256, 256, 0, stream>>>(idx, cur, bucket);
  gather_kernel<<<(NNODE + 7) / 8, 256, 0, stream>>>(e2, bucket, noff, cnt, v);
  mlp_kernel<<<NNODE / 64, 256, 0, stream>>>(v, wtup, bup, wtlin, blin, Wout, out);
}

// Round 3
// 298.143 us; speedup vs baseline: 3.9464x; 1.0184x over previous
//
#include <hip/hip_runtime.h>

#define HID 128
#define EMB 256
#define NL 3
#define NEDGE 640000
#define NNODE 40000
#define SCAN_T 1024
#define CHUNK 40  // ceil(NNODE / SCAN_T)

typedef unsigned short u16;
typedef __attribute__((ext_vector_type(8))) __bf16 bf16x8;
typedef __attribute__((ext_vector_type(4))) float f32x4;

union Frag {
  uint4 q;
  bf16x8 v;
  u16 u[8];
};

__device__ inline u16 f2b(float f) {
  unsigned u = __float_as_uint(f);
  unsigned r = (u + 0x7fffu + ((u >> 16) & 1u)) >> 16;  // RNE
  return (u16)r;
}
__device__ inline float b2f(u16 h) { return __uint_as_float(((unsigned)h) << 16); }

// swizzled index into a [64][EMB] bf16 LDS tile (row stride 512 B).
// XOR byte-bits 4..6 with row&7: 8-row stripes cover all 32 banks (G4).
__device__ inline int sidx(int row, int k) {
  return row * EMB + ((((k) << 1) ^ ((row & 7) << 4)) >> 1);
}

// -------- weight prep: f32 -> bf16, transposed to [col][k]; also zeros cnt ----
__global__ void prep_weights(const float* __restrict__ Wup, const float* __restrict__ Wlins,
                             u16* __restrict__ wtup, u16* __restrict__ wtlin,
                             int* __restrict__ cnt) {
  int t = blockIdx.x * blockDim.x + threadIdx.x;
  if (t < NNODE) cnt[t] = 0;  // replaces hipMemsetAsync (190 us fillBuffer pathology)
  if (t < EMB * HID) {
    int c = t >> 7, k = t & (HID - 1);
    wtup[t] = f2b(Wup[k * EMB + c]);
  }
  if (t < NL * EMB * EMB) {
    int l = t >> 16, r = t & 0xFFFF;
    int c = r >> 8, k = r & 255;
    wtlin[t] = f2b(Wlins[l * EMB * EMB + k * EMB + c]);
  }
}

// ---------------- CSR build ----------------
__global__ void count_kernel(const int* __restrict__ idx, int* __restrict__ cnt) {
  int e = blockIdx.x * blockDim.x + threadIdx.x;
  if (e < NEDGE) atomicAdd(&cnt[idx[e]], 1);
}

__global__ __launch_bounds__(SCAN_T) void scan_kernel(const int* __restrict__ cnt,
                                                      int* __restrict__ off,
                                                      int* __restrict__ cur) {
  __shared__ int s[SCAN_T];
  int t = threadIdx.x;
  int base = t * CHUNK;
  int c[CHUNK];
  int local = 0;
#pragma unroll
  for (int j = 0; j < CHUNK; ++j) {
    int i = base + j;
    c[j] = (i < NNODE) ? cnt[i] : 0;
    local += c[j];
  }
  s[t] = local;
  __syncthreads();
  for (int d = 1; d < SCAN_T; d <<= 1) {
    int tmp = (t >= d) ? s[t - d] : 0;
    __syncthreads();
    s[t] += tmp;
    __syncthreads();
  }
  int run = (t == 0) ? 0 : s[t - 1];  // exclusive prefix of per-thread sums
#pragma unroll
  for (int j = 0; j < CHUNK; ++j) {
    int i = base + j;
    if (i < NNODE) { off[i] = run; cur[i] = run; }
    run += c[j];
  }
}

__global__ void fill_kernel(const int* __restrict__ idx, int* __restrict__ cur,
                            int* __restrict__ bucket) {
  int e = blockIdx.x * blockDim.x + threadIdx.x;
  if (e < NEDGE) {
    int p = atomicAdd(&cur[idx[e]], 1);
    bucket[p] = e;
  }
}

// ---------------- gather-sum: v[node] = sum of its e2 rows ----------------
__global__ __launch_bounds__(256) void gather_kernel(const float* __restrict__ e2,
                                                     const int* __restrict__ bucket,
                                                     const int* __restrict__ off,
                                                     const int* __restrict__ cnt,
                                                     float* __restrict__ v) {
  int node = blockIdx.x * 8 + (threadIdx.x >> 5);  // 32 lanes per node
  if (node >= NNODE) return;
  int lane = threadIdx.x & 31;
  int s = off[node];
  int n = cnt[node];
  float4 acc = {0.f, 0.f, 0.f, 0.f};
  int e = (n > 0) ? bucket[s] : 0;
  for (int j = 0; j < n; ++j) {
    int enext = (j + 1 < n) ? bucket[s + j + 1] : 0;  // prefetch next edge id
    const float4 x = *reinterpret_cast<const float4*>(e2 + (size_t)e * HID + lane * 4);
    acc.x += x.x; acc.y += x.y; acc.z += x.z; acc.w += x.w;
    e = enext;
  }
  *reinterpret_cast<float4*>(v + (size_t)node * HID + lane * 4) = acc;
}

// ---------------- fused MLP: 64 rows per block, 4 waves, bf16 MFMA ----------
__global__ __launch_bounds__(256, 2) void mlp_kernel(
    const float* __restrict__ v,      // [N][HID] f32 (gather output)
    const u16* __restrict__ wtup,     // [EMB][HID] bf16 = W_up^T
    const float* __restrict__ bup,    // [EMB]
    const u16* __restrict__ wtlin,    // [NL][EMB][EMB] bf16 = W_lin^T per layer
    const float* __restrict__ blin,   // [NL][EMB]
    const float* __restrict__ wout,   // [EMB] f32
    float* __restrict__ out) {        // [N]
  __shared__ __attribute__((aligned(16))) u16 actA[64 * EMB];
  __shared__ __attribute__((aligned(16))) u16 actB[64 * EMB];

  const int tid = threadIdx.x;
  const int wv = tid >> 6;     // wave 0..3 owns cols wv*64 .. wv*64+63
  const int lane = tid & 63;
  const int l16 = lane & 15;
  const int kg = lane >> 4;    // k-group 0..3
  const int row0 = blockIdx.x * 64;

  f32x4 acc[4][4];

  // ---------- layer 1: v[64x128] @ W_up + b_up (no activation) ----------
#pragma unroll
  for (int rt = 0; rt < 4; ++rt)
#pragma unroll
    for (int ct = 0; ct < 4; ++ct)
      acc[rt][ct] = (f32x4)(0.f);

#pragma unroll
  for (int ks = 0; ks < HID / 32; ++ks) {
    Frag bf[4];
#pragma unroll
    for (int ct = 0; ct < 4; ++ct) {
      int col = wv * 64 + ct * 16 + l16;
      bf[ct].q = *reinterpret_cast<const uint4*>(wtup + col * HID + ks * 32 + kg * 8);
    }
#pragma unroll
    for (int rt = 0; rt < 4; ++rt) {
      const float* src = v + (size_t)(row0 + rt * 16 + l16) * HID + ks * 32 + kg * 8;
      float4 x0 = *reinterpret_cast<const float4*>(src);
      float4 x1 = *reinterpret_cast<const float4*>(src + 4);
      Frag af;
      af.u[0] = f2b(x0.x); af.u[1] = f2b(x0.y); af.u[2] = f2b(x0.z); af.u[3] = f2b(x0.w);
      af.u[4] = f2b(x1.x); af.u[5] = f2b(x1.y); af.u[6] = f2b(x1.z); af.u[7] = f2b(x1.w);
#pragma unroll
      for (int ct = 0; ct < 4; ++ct)
        acc[rt][ct] = __builtin_amdgcn_mfma_f32_16x16x32_bf16(af.v, bf[ct].v, acc[rt][ct], 0, 0, 0);
    }
  }
  // epilogue: + bias, store bf16 into actA (C layout: row=(lane>>4)*4+i, col=lane&15)
#pragma unroll
  for (int ct = 0; ct < 4; ++ct) {
    int col = wv * 64 + ct * 16 + l16;
    float b = bup[col];
#pragma unroll
    for (int rt = 0; rt < 4; ++rt)
#pragma unroll
      for (int i = 0; i < 4; ++i)
        actA[sidx(rt * 16 + kg * 4 + i, col)] = f2b(acc[rt][ct][i] + b);
  }
  __syncthreads();

  // ---------- layers 2..4: silu(h @ W + b) ----------
  const u16* sbuf = actA;
  u16* dbuf = actB;
  for (int l = 0; l < NL; ++l) {
    const u16* wt = wtlin + l * EMB * EMB;
    const float* bl = blin + l * EMB;
#pragma unroll
    for (int rt = 0; rt < 4; ++rt)
#pragma unroll
      for (int ct = 0; ct < 4; ++ct)
        acc[rt][ct] = (f32x4)(0.f);

#pragma unroll
    for (int ks = 0; ks < EMB / 32; ++ks) {
      Frag bf[4];
#pragma unroll
      for (int ct = 0; ct < 4; ++ct) {
        int col = wv * 64 + ct * 16 + l16;
        bf[ct].q = *reinterpret_cast<const uint4*>(wt + col * EMB + ks * 32 + kg * 8);
      }
#pragma unroll
      for (int rt = 0; rt < 4; ++rt) {
        Frag af;
        af.q = *reinterpret_cast<const uint4*>(&sbuf[sidx(rt * 16 + l16, ks * 32 + kg * 8)]);
#pragma unroll
        for (int ct = 0; ct < 4; ++ct)
          acc[rt][ct] = __builtin_amdgcn_mfma_f32_16x16x32_bf16(af.v, bf[ct].v, acc[rt][ct], 0, 0, 0);
      }
    }
    // epilogue: bias + silu + store
#pragma unroll
    for (int ct = 0; ct < 4; ++ct) {
      int col = wv * 64 + ct * 16 + l16;
      float b = bl[col];
#pragma unroll
      for (int rt = 0; rt < 4; ++rt)
#pragma unroll
        for (int i = 0; i < 4; ++i) {
          float x = acc[rt][ct][i] + b;
          float s = x / (1.f + __expf(-x));
          dbuf[sidx(rt * 16 + kg * 4 + i, col)] = f2b(s);
        }
    }
    __syncthreads();
    const u16* tmp = dbuf;
    dbuf = const_cast<u16*>(sbuf);
    sbuf = tmp;
  }

  // ---------- final projection: out = h @ W_out (K=256, N=1) ----------
  int r = tid >> 2;
  int part = tid & 3;
  float s = 0.f;
  int k0 = part * 64;
  for (int k = k0; k < k0 + 64; ++k)
    s += b2f(sbuf[sidx(r, k)]) * wout[k];
  s += __shfl_xor(s, 1);
  s += __shfl_xor(s, 2);
  if (part == 0) out[row0 + r] = s;
}

extern "C" void kernel_launch(void* const* d_in, const int* in_sizes, int n_in,
                              void* d_out, int out_size, void* d_ws, size_t ws_size,
                              hipStream_t stream) {
  // inputs: 0=e1(unused) 1=e2 2=i 3=num_nodes 4=W_up 5=b_up 6=W_lins 7=b_lins 8=W_out
  const float* e2 = (const float*)d_in[1];
  const int* idx = (const int*)d_in[2];
  const float* Wup = (const float*)d_in[4];
  const float* bup = (const float*)d_in[5];
  const float* Wlins = (const float*)d_in[6];
  const float* blin = (const float*)d_in[7];
  const float* Wout = (const float*)d_in[8];
  float* out = (float*)d_out;

  // workspace layout
  char* ws = (char*)d_ws;
  size_t off_b = 0;
  float* v = (float*)(ws + off_b);            off_b += (size_t)NNODE * HID * sizeof(float);   // 20.48 MB
  u16* wtup = (u16*)(ws + off_b);             off_b += (size_t)EMB * HID * sizeof(u16);
  u16* wtlin = (u16*)(ws + off_b);            off_b += (size_t)NL * EMB * EMB * sizeof(u16);
  int* cnt = (int*)(ws + off_b);              off_b += (size_t)NNODE * sizeof(int);
  int* noff = (int*)(ws + off_b);             off_b += (size_t)NNODE * sizeof(int);
  int* cur = (int*)(ws + off_b);              off_b += (size_t)NNODE * sizeof(int);
  int* bucket = (int*)(ws + off_b);           off_b += (size_t)NEDGE * sizeof(int);

  prep_weights<<<(NL * EMB * EMB + 255) / 256, 256, 0, stream>>>(Wup, Wlins, wtup, wtlin, cnt);
  count_kernel<<<(NEDGE + 255) / 256, 256, 0, stream>>>(idx, cnt);
  scan_kernel<<<1, SCAN_T, 0, stream>>>(cnt, noff, cur);
  fill_kernel<<<(NEDGE + 255) / 256, 256, 0, stream>>>(idx, cur, bucket);
  gather_kernel<<<(NNODE + 7) / 8, 256, 0, stream>>>(e2, bucket, noff, cnt, v);
  mlp_kernel<<<NNODE / 64, 256, 0, stream>>>(v, wtup, bup, wtlin, blin, Wout, out);
}

// Round 4
// 233.637 us; speedup vs baseline: 5.0359x; 1.2761x over previous
//
#include <hip/hip_runtime.h>

#define HID 128
#define EMB 256
#define NL 3
#define NEDGE 640000
#define NNODE 40000
#define SCAN_BS 256
#define SCAN_ELEM 1024           // elements per scan block (4 per thread)
#define SCAN_NB 40               // ceil(NNODE / SCAN_ELEM)

typedef unsigned short u16;
typedef __attribute__((ext_vector_type(8))) __bf16 bf16x8;
typedef __attribute__((ext_vector_type(4))) float f32x4;

union Frag {
  uint4 q;
  bf16x8 v;
  u16 u[8];
};

__device__ inline u16 f2b(float f) {
  unsigned u = __float_as_uint(f);
  unsigned r = (u + 0x7fffu + ((u >> 16) & 1u)) >> 16;  // RNE
  return (u16)r;
}
__device__ inline float b2f(u16 h) { return __uint_as_float(((unsigned)h) << 16); }

// swizzled index into a [64][EMB] bf16 LDS tile (row stride 512 B).
__device__ inline int sidx(int row, int k) {
  return row * EMB + ((((k) << 1) ^ ((row & 7) << 4)) >> 1);
}

// -------- weight prep: f32 -> bf16, transposed to [col][k]; also zeros cnt ----
__global__ void prep_weights(const float* __restrict__ Wup, const float* __restrict__ Wlins,
                             u16* __restrict__ wtup, u16* __restrict__ wtlin,
                             int* __restrict__ cnt) {
  int t = blockIdx.x * blockDim.x + threadIdx.x;
  if (t < NNODE) cnt[t] = 0;
  if (t < EMB * HID) {
    int c = t >> 7, k = t & (HID - 1);
    wtup[t] = f2b(Wup[k * EMB + c]);
  }
  if (t < NL * EMB * EMB) {
    int l = t >> 16, r = t & 0xFFFF;
    int c = r >> 8, k = r & 255;
    wtlin[t] = f2b(Wlins[l * EMB * EMB + k * EMB + c]);
  }
}

// ---------------- CSR build ----------------
__global__ void count_kernel(const int* __restrict__ idx, int* __restrict__ cnt) {
  int t = blockIdx.x * blockDim.x + threadIdx.x;  // < NEDGE/4
  int4 id = reinterpret_cast<const int4*>(idx)[t];
  atomicAdd(&cnt[id.x], 1);
  atomicAdd(&cnt[id.y], 1);
  atomicAdd(&cnt[id.z], 1);
  atomicAdd(&cnt[id.w], 1);
}

// block-level exclusive scan: 40 blocks x 1024 elements (4/thread, coalesced int4)
__global__ __launch_bounds__(SCAN_BS) void scan_part(const int* __restrict__ cnt,
                                                     int* __restrict__ off,
                                                     int* __restrict__ bsum) {
  __shared__ int s[SCAN_BS];
  int t = threadIdx.x;
  int i4 = blockIdx.x * SCAN_BS + t;  // int4 index
  int4 c = {0, 0, 0, 0};
  if (i4 * 4 < NNODE) c = reinterpret_cast<const int4*>(cnt)[i4];
  int tsum = c.x + c.y + c.z + c.w;
  s[t] = tsum;
  __syncthreads();
  for (int d = 1; d < SCAN_BS; d <<= 1) {
    int v = (t >= d) ? s[t - d] : 0;
    __syncthreads();
    s[t] += v;
    __syncthreads();
  }
  int excl = (t == 0) ? 0 : s[t - 1];
  if (t == SCAN_BS - 1) bsum[blockIdx.x] = s[t];
  int4 o;
  o.x = excl;
  o.y = o.x + c.x;
  o.z = o.y + c.y;
  o.w = o.z + c.z;
  if (i4 * 4 < NNODE) reinterpret_cast<int4*>(off)[i4] = o;
}

__global__ void scan_top(int* __restrict__ bsum, int* __restrict__ bbase) {
  // single thread: 40 values
  int run = 0;
  for (int b = 0; b < SCAN_NB; ++b) {
    bbase[b] = run;
    run += bsum[b];
  }
}

__global__ __launch_bounds__(SCAN_BS) void scan_add(int* __restrict__ off,
                                                    int* __restrict__ cur,
                                                    const int* __restrict__ bbase) {
  int t = threadIdx.x;
  int i4 = blockIdx.x * SCAN_BS + t;
  if (i4 * 4 >= NNODE) return;
  int base = bbase[blockIdx.x];
  int4 o = reinterpret_cast<int4*>(off)[i4];
  o.x += base; o.y += base; o.z += base; o.w += base;
  reinterpret_cast<int4*>(off)[i4] = o;
  reinterpret_cast<int4*>(cur)[i4] = o;
}

__global__ void fill_kernel(const int* __restrict__ idx, int* __restrict__ cur,
                            int* __restrict__ bucket) {
  int t = blockIdx.x * blockDim.x + threadIdx.x;  // < NEDGE/4
  int4 id = reinterpret_cast<const int4*>(idx)[t];
  int e0 = t * 4;
  int p;
  p = atomicAdd(&cur[id.x], 1); bucket[p] = e0;
  p = atomicAdd(&cur[id.y], 1); bucket[p] = e0 + 1;
  p = atomicAdd(&cur[id.z], 1); bucket[p] = e0 + 2;
  p = atomicAdd(&cur[id.w], 1); bucket[p] = e0 + 3;
}

// ---------------- gather-sum: v[node] = sum of its e2 rows ----------------
// 16 lanes per node, 2 float4 per lane -> ILP 2, ~16 MB in flight at full occupancy
__global__ __launch_bounds__(256) void gather_kernel(const float* __restrict__ e2,
                                                     const int* __restrict__ bucket,
                                                     const int* __restrict__ off,
                                                     const int* __restrict__ cnt,
                                                     float* __restrict__ v) {
  int node = blockIdx.x * 16 + (threadIdx.x >> 4);
  int lane = threadIdx.x & 15;  // floats [lane*8, lane*8+8)
  int s = off[node];
  int n = cnt[node];
  float4 a0 = {0.f, 0.f, 0.f, 0.f};
  float4 a1 = {0.f, 0.f, 0.f, 0.f};
  int e = (n > 0) ? bucket[s] : 0;
  for (int j = 0; j < n; ++j) {
    int en = (j + 1 < n) ? bucket[s + j + 1] : 0;
    const float* r = e2 + (size_t)e * HID + lane * 8;
    float4 x0 = *reinterpret_cast<const float4*>(r);
    float4 x1 = *reinterpret_cast<const float4*>(r + 4);
    a0.x += x0.x; a0.y += x0.y; a0.z += x0.z; a0.w += x0.w;
    a1.x += x1.x; a1.y += x1.y; a1.z += x1.z; a1.w += x1.w;
    e = en;
  }
  float* dst = v + (size_t)node * HID + lane * 8;
  *reinterpret_cast<float4*>(dst) = a0;
  *reinterpret_cast<float4*>(dst + 4) = a1;
}

// ---------------- fused MLP: 64 rows per block, 4 waves, bf16 MFMA ----------
__global__ __launch_bounds__(256, 2) void mlp_kernel(
    const float* __restrict__ v,      // [N][HID] f32 (gather output)
    const u16* __restrict__ wtup,     // [EMB][HID] bf16 = W_up^T
    const float* __restrict__ bup,    // [EMB]
    const u16* __restrict__ wtlin,    // [NL][EMB][EMB] bf16 = W_lin^T per layer
    const float* __restrict__ blin,   // [NL][EMB]
    const float* __restrict__ wout,   // [EMB] f32
    float* __restrict__ out) {        // [N]
  __shared__ __attribute__((aligned(16))) u16 actA[64 * EMB];
  __shared__ __attribute__((aligned(16))) u16 actB[64 * EMB];

  const int tid = threadIdx.x;
  const int wv = tid >> 6;
  const int lane = tid & 63;
  const int l16 = lane & 15;
  const int kg = lane >> 4;
  const int row0 = blockIdx.x * 64;

  f32x4 acc[4][4];

#pragma unroll
  for (int rt = 0; rt < 4; ++rt)
#pragma unroll
    for (int ct = 0; ct < 4; ++ct)
      acc[rt][ct] = (f32x4)(0.f);

#pragma unroll
  for (int ks = 0; ks < HID / 32; ++ks) {
    Frag bf[4];
#pragma unroll
    for (int ct = 0; ct < 4; ++ct) {
      int col = wv * 64 + ct * 16 + l16;
      bf[ct].q = *reinterpret_cast<const uint4*>(wtup + col * HID + ks * 32 + kg * 8);
    }
#pragma unroll
    for (int rt = 0; rt < 4; ++rt) {
      const float* src = v + (size_t)(row0 + rt * 16 + l16) * HID + ks * 32 + kg * 8;
      float4 x0 = *reinterpret_cast<const float4*>(src);
      float4 x1 = *reinterpret_cast<const float4*>(src + 4);
      Frag af;
      af.u[0] = f2b(x0.x); af.u[1] = f2b(x0.y); af.u[2] = f2b(x0.z); af.u[3] = f2b(x0.w);
      af.u[4] = f2b(x1.x); af.u[5] = f2b(x1.y); af.u[6] = f2b(x1.z); af.u[7] = f2b(x1.w);
#pragma unroll
      for (int ct = 0; ct < 4; ++ct)
        acc[rt][ct] = __builtin_amdgcn_mfma_f32_16x16x32_bf16(af.v, bf[ct].v, acc[rt][ct], 0, 0, 0);
    }
  }
#pragma unroll
  for (int ct = 0; ct < 4; ++ct) {
    int col = wv * 64 + ct * 16 + l16;
    float b = bup[col];
#pragma unroll
    for (int rt = 0; rt < 4; ++rt)
#pragma unroll
      for (int i = 0; i < 4; ++i)
        actA[sidx(rt * 16 + kg * 4 + i, col)] = f2b(acc[rt][ct][i] + b);
  }
  __syncthreads();

  const u16* sbuf = actA;
  u16* dbuf = actB;
  for (int l = 0; l < NL; ++l) {
    const u16* wt = wtlin + l * EMB * EMB;
    const float* bl = blin + l * EMB;
#pragma unroll
    for (int rt = 0; rt < 4; ++rt)
#pragma unroll
      for (int ct = 0; ct < 4; ++ct)
        acc[rt][ct] = (f32x4)(0.f);

#pragma unroll
    for (int ks = 0; ks < EMB / 32; ++ks) {
      Frag bf[4];
#pragma unroll
      for (int ct = 0; ct < 4; ++ct) {
        int col = wv * 64 + ct * 16 + l16;
        bf[ct].q = *reinterpret_cast<const uint4*>(wt + col * EMB + ks * 32 + kg * 8);
      }
#pragma unroll
      for (int rt = 0; rt < 4; ++rt) {
        Frag af;
        af.q = *reinterpret_cast<const uint4*>(&sbuf[sidx(rt * 16 + l16, ks * 32 + kg * 8)]);
#pragma unroll
        for (int ct = 0; ct < 4; ++ct)
          acc[rt][ct] = __builtin_amdgcn_mfma_f32_16x16x32_bf16(af.v, bf[ct].v, acc[rt][ct], 0, 0, 0);
      }
    }
#pragma unroll
    for (int ct = 0; ct < 4; ++ct) {
      int col = wv * 64 + ct * 16 + l16;
      float b = bl[col];
#pragma unroll
      for (int rt = 0; rt < 4; ++rt)
#pragma unroll
        for (int i = 0; i < 4; ++i) {
          float x = acc[rt][ct][i] + b;
          float s = x / (1.f + __expf(-x));
          dbuf[sidx(rt * 16 + kg * 4 + i, col)] = f2b(s);
        }
    }
    __syncthreads();
    const u16* tmp = dbuf;
    dbuf = const_cast<u16*>(sbuf);
    sbuf = tmp;
  }

  int r = tid >> 2;
  int part = tid & 3;
  float s = 0.f;
  int k0 = part * 64;
  for (int k = k0; k < k0 + 64; ++k)
    s += b2f(sbuf[sidx(r, k)]) * wout[k];
  s += __shfl_xor(s, 1);
  s += __shfl_xor(s, 2);
  if (part == 0) out[row0 + r] = s;
}

extern "C" void kernel_launch(void* const* d_in, const int* in_sizes, int n_in,
                              void* d_out, int out_size, void* d_ws, size_t ws_size,
                              hipStream_t stream) {
  const float* e2 = (const float*)d_in[1];
  const int* idx = (const int*)d_in[2];
  const float* Wup = (const float*)d_in[4];
  const float* bup = (const float*)d_in[5];
  const float* Wlins = (const float*)d_in[6];
  const float* blin = (const float*)d_in[7];
  const float* Wout = (const float*)d_in[8];
  float* out = (float*)d_out;

  char* ws = (char*)d_ws;
  size_t off_b = 0;
  float* v = (float*)(ws + off_b);   off_b += (size_t)NNODE * HID * sizeof(float);
  u16* wtup = (u16*)(ws + off_b);    off_b += (size_t)EMB * HID * sizeof(u16);
  u16* wtlin = (u16*)(ws + off_b);   off_b += (size_t)NL * EMB * EMB * sizeof(u16);
  int* cnt = (int*)(ws + off_b);     off_b += (size_t)NNODE * sizeof(int);
  int* noff = (int*)(ws + off_b);    off_b += (size_t)NNODE * sizeof(int);
  int* cur = (int*)(ws + off_b);     off_b += (size_t)NNODE * sizeof(int);
  int* bucket = (int*)(ws + off_b);  off_b += (size_t)NEDGE * sizeof(int);
  int* bsum = (int*)(ws + off_b);    off_b += 64 * sizeof(int);
  int* bbase = (int*)(ws + off_b);   off_b += 64 * sizeof(int);

  prep_weights<<<(NL * EMB * EMB + 255) / 256, 256, 0, stream>>>(Wup, Wlins, wtup, wtlin, cnt);
  count_kernel<<<NEDGE / 4 / 256, 256, 0, stream>>>(idx, cnt);
  scan_part<<<SCAN_NB, SCAN_BS, 0, stream>>>(cnt, noff, bsum);
  scan_top<<<1, 1, 0, stream>>>(bsum, bbase);
  scan_add<<<SCAN_NB, SCAN_BS, 0, stream>>>(noff, cur, bbase);
  fill_kernel<<<NEDGE / 4 / 256, 256, 0, stream>>>(idx, cur, bucket);
  gather_kernel<<<NNODE / 16, 256, 0, stream>>>(e2, bucket, noff, cnt, v);
  mlp_kernel<<<NNODE / 64, 256, 0, stream>>>(v, wtup, bup, wtlin, blin, Wout, out);
}